// Round 5
// baseline (412.737 us; speedup 1.0000x reference)
//
#include <hip/hip_runtime.h>
#include <math.h>

#define NE 256
#define EDIM 1024
#define HW 1024
#define NPIX 16384
#define OUT_ELEMS 16777216

typedef short short8 __attribute__((ext_vector_type(8)));
typedef float f32x4 __attribute__((ext_vector_type(4)));

// ---------------- fast-path workspace layout (bytes) ----------------
// [memset region: hist + ctrl + T]
#define WS_HIST   0          // int[256]
#define WS_LOSS   1024       // float
#define WS_ZSQ    1028       // float
#define WS_NFLAG  1032       // int
#define WS_T      4096       // float[1024*256] = 1 MB
#define WS_MEMSET 1052672
// [no-init region]
#define WS_CE2    1052672    // float[256]
#define WS_FLAG   1053696    // int[16384]
#define WS_IDX    1119232    // int[16384]
#define WS_EH     1184768    // ushort[256*1024] = 512 KB
#define WS_NEED   1709056

#define MAXF 16384           // can hold ALL pixels -> overflow can't drop any
#define DELTA 0.6f           // tie-guard; 1-pass bf16 score-diff sigma ~0.07-0.1

// ---------------- fallback (round-1) workspace layout ----------------
#define WO_CE2  0
#define WO_HIST 1024
#define WO_LOSS 2048
#define WO_IDX  4096
#define WO_T    69632
#define WO_TOTAL 1118208

__device__ __forceinline__ unsigned short f2bf(float f) {
    unsigned u = __float_as_uint(f);
    unsigned r = u + 0x7FFFu + ((u >> 16) & 1u);   // RNE
    return (unsigned short)(r >> 16);
}

// ---------------- ce2[j] = 0.5*||emb_j||^2 (exact fp32) ----------------
__global__ __launch_bounds__(64) void k_norms(const float* __restrict__ emb,
                                              float* __restrict__ ce2) {
    int j = blockIdx.x;
    int lane = threadIdx.x;
    const float* row = emb + (size_t)j * EDIM;
    float s = 0.f;
    #pragma unroll
    for (int i = 0; i < EDIM / 64; i++) {
        float v = row[lane + 64 * i];
        s += v * v;
    }
    #pragma unroll
    for (int m = 32; m; m >>= 1) s += __shfl_down(s, m, 64);
    if (lane == 0) ce2[j] = 0.5f * s;
}

// ---------------- T[o][j] = sum_c w[o][c]*emb[j][c] (split-K, atomics) ----
__global__ __launch_bounds__(256) void k_wT(const float* __restrict__ w,
                                            const float* __restrict__ emb,
                                            float* __restrict__ T) {
    __shared__ float wt[64 * 17];
    __shared__ float et[64 * 17];
    int t = threadIdx.x;
    int j0 = blockIdx.x * 64;
    int o0 = blockIdx.y * 64;
    int kb = blockIdx.z * 256;
    int to = t & 15, tj = t >> 4;
    float acc[4][4] = {};
    int lr = t >> 2, lk = (t & 3) * 4;
    for (int kk = kb; kk < kb + 256; kk += 16) {
        float4 wv = *(const float4*)(w + (size_t)(o0 + lr) * EDIM + kk + lk);
        float4 ev = *(const float4*)(emb + (size_t)(j0 + lr) * EDIM + kk + lk);
        __syncthreads();
        wt[lr * 17 + lk + 0] = wv.x; wt[lr * 17 + lk + 1] = wv.y;
        wt[lr * 17 + lk + 2] = wv.z; wt[lr * 17 + lk + 3] = wv.w;
        et[lr * 17 + lk + 0] = ev.x; et[lr * 17 + lk + 1] = ev.y;
        et[lr * 17 + lk + 2] = ev.z; et[lr * 17 + lk + 3] = ev.w;
        __syncthreads();
        #pragma unroll
        for (int k = 0; k < 16; k++) {
            float a[4], b[4];
            #pragma unroll
            for (int i = 0; i < 4; i++) a[i] = wt[(to * 4 + i) * 17 + k];
            #pragma unroll
            for (int i = 0; i < 4; i++) b[i] = et[(tj * 4 + i) * 17 + k];
            #pragma unroll
            for (int i = 0; i < 4; i++)
                #pragma unroll
                for (int jx = 0; jx < 4; jx++) acc[i][jx] += a[i] * b[jx];
        }
    }
    #pragma unroll
    for (int i = 0; i < 4; i++)
        #pragma unroll
        for (int jx = 0; jx < 4; jx++)
            atomicAdd(&T[(size_t)(o0 + to * 4 + i) * NE + j0 + tj * 4 + jx],
                      acc[i][jx]);
}

// ---------------- prep: emb fp32 -> eh bf16 [code][k] ----------------------
__global__ __launch_bounds__(256) void k_prep_e(const float* __restrict__ emb,
                                                unsigned short* __restrict__ eh) {
    int i = (blockIdx.x * 256 + threadIdx.x) * 4;
    float4 v = *(const float4*)(emb + i);
    uint2 hp;
    hp.x = (unsigned)f2bf(v.x) | ((unsigned)f2bf(v.y) << 16);
    hp.y = (unsigned)f2bf(v.z) | ((unsigned)f2bf(v.w) << 16);
    *(uint2*)(eh + i) = hp;
}

// ---------------- fused distance GEMM + argmin + tie-flagging --------------
// 1024 blocks x 256 thr (4 waves). Each block: 16 px, all 256 codes.
// Split-K x4: wave w covers K in [w*256, w*256+256) = 8 chunks of 32.
// A (z) converted fp32->bf16 inline; B (eh) straight from L2. No K-loop
// barriers; one LDS tree-combine at the end. 3 blocks/CU (52 KB LDS) ->
// 12 waves/CU for latency hiding.
__global__ __launch_bounds__(256, 3) void k_dist(
        const float* __restrict__ z, const unsigned short* __restrict__ eh,
        const float* __restrict__ ce2,
        int* __restrict__ idx_i, float* __restrict__ idx_f,
        int* __restrict__ hist, float* __restrict__ loss_s,
        float* __restrict__ zsq_acc,
        int* __restrict__ nflag, int* __restrict__ flagged) {
    __shared__ float accbuf[3 * 64 * 68];   // waves 1..3 acc spill
    int t = threadIdx.x;
    int lane = t & 63, w = t >> 6;
    int m = lane & 15, quad = lane >> 4;
    int px0 = blockIdx.x * 16;          // 16-px groups never cross a batch image
    int b = px0 >> 10;
    const float* zp = z + (((size_t)b) << 20) + (px0 & 1023) + m;  // + (c<<10)
    int k0 = w * 256;

    f32x4 acc[16];
    #pragma unroll
    for (int nt = 0; nt < 16; nt++) acc[nt] = (f32x4){0.f, 0.f, 0.f, 0.f};

    float zsq = 0.f;
    float zv[8];
    #pragma unroll
    for (int j = 0; j < 8; j++)         // prefetch A chunk 0
        zv[j] = zp[((size_t)(k0 + quad * 8 + j)) << 10];

    for (int ck = 0; ck < 8; ck++) {
        int kk = k0 + ck * 32;
        short8 bf[16];
        #pragma unroll
        for (int nt = 0; nt < 16; nt++)  // B frag: code = nt*16+m, k = kk+quad*8..+8
            bf[nt] = *(const short8*)(eh + (((size_t)(nt * 16 + m)) << 10) + kk + quad * 8);
        short8 af;
        #pragma unroll
        for (int j = 0; j < 8; j++) {
            zsq += zv[j] * zv[j];
            ((unsigned short*)&af)[j] = f2bf(zv[j]);
        }
        if (ck < 7) {
            #pragma unroll
            for (int j = 0; j < 8; j++)  // prefetch next A under this chunk's MFMAs
                zv[j] = zp[((size_t)(kk + 32 + quad * 8 + j)) << 10];
        }
        #pragma unroll
        for (int nt = 0; nt < 16; nt++)
            acc[nt] = __builtin_amdgcn_mfma_f32_16x16x32_bf16(af, bf[nt], acc[nt], 0, 0, 0);
    }

    // zsq: waves cover disjoint (px,k) -> all contribute
    #pragma unroll
    for (int msk = 32; msk; msk >>= 1) zsq += __shfl_down(zsq, msk, 64);
    if (lane == 0) atomicAdd(zsq_acc, zsq);

    if (w > 0) {
        float* reg = accbuf + (size_t)(w - 1) * 64 * 68 + lane * 68;
        #pragma unroll
        for (int nt = 0; nt < 16; nt++)
            *(f32x4*)(reg + nt * 4) = acc[nt];
    }
    __syncthreads();
    if (w == 0) {
        #pragma unroll
        for (int r = 0; r < 3; r++) {
            const float* reg = accbuf + (size_t)r * 64 * 68 + lane * 68;
            #pragma unroll
            for (int nt = 0; nt < 16; nt++) {
                f32x4 o = *(const f32x4*)(reg + nt * 4);
                acc[nt][0] += o[0]; acc[nt][1] += o[1];
                acc[nt][2] += o[2]; acc[nt][3] += o[3];
            }
        }
        float c2v[16];
        #pragma unroll
        for (int nt = 0; nt < 16; nt++) c2v[nt] = ce2[nt * 16 + m];

        float lsum = 0.f;
        #pragma unroll
        for (int r = 0; r < 4; r++) {    // D layout: row(px) = quad*4+r, col(code) = m
            float v1 = 3.4e38f, v2 = 3.4e38f; int i1 = 0;
            #pragma unroll
            for (int nt = 0; nt < 16; nt++) {
                int code = nt * 16 + m;
                float sv = c2v[nt] - acc[nt][r];   // 0.5||e||^2 - z.e
                if (sv < v1 || (sv == v1 && code < i1)) { v2 = v1; v1 = sv; i1 = code; }
                else v2 = fminf(v2, sv);
            }
            #pragma unroll
            for (int msk = 1; msk < 16; msk <<= 1) {
                float ov1 = __shfl_xor(v1, msk, 64);
                int   oi1 = __shfl_xor(i1, msk, 64);
                float ov2 = __shfl_xor(v2, msk, 64);
                float nv2 = fminf(fminf(v2, ov2), fmaxf(v1, ov1));
                if (ov1 < v1 || (ov1 == v1 && oi1 < i1)) { v1 = ov1; i1 = oi1; }
                v2 = nv2;
            }
            if (m == 0) {
                int px = px0 + quad * 4 + r;
                idx_i[px] = i1;
                idx_f[px] = (float)i1;
                atomicAdd(&hist[i1], 1);
                if (v2 - v1 < DELTA) {
                    int pos = atomicAdd(nflag, 1);
                    if (pos < MAXF) flagged[pos] = px;
                }
                lsum += v1;
            }
        }
        lsum += __shfl_xor(lsum, 16, 64);
        lsum += __shfl_xor(lsum, 32, 64);
        if (lane == 0) atomicAdd(loss_s, lsum);
    }
}

// ---------------- exact fp32 re-argmin for tie-flagged pixels --------------
__global__ __launch_bounds__(256) void k_cleanup(const float* __restrict__ z,
        const float* __restrict__ emb, const float* __restrict__ ce2,
        const int* __restrict__ nflag, const int* __restrict__ flagged,
        int* __restrict__ idx_i, float* __restrict__ idx_f, int* __restrict__ hist) {
    __shared__ float zs[1024];
    __shared__ float rv[4];
    __shared__ int ri[4];
    int t = threadIdx.x;
    int nf = *nflag; if (nf > MAXF) nf = MAXF;
    const float* er = emb + (size_t)t * EDIM;
    for (int i = blockIdx.x; i < nf; i += gridDim.x) {
        int px = flagged[i];
        int b = px >> 10, p = px & 1023;
        const float* zb = z + (((size_t)b) << 20) + p;
        #pragma unroll
        for (int r = 0; r < 4; r++) {
            int c = t + 256 * r;
            zs[c] = zb[((size_t)c) << 10];
        }
        __syncthreads();
        float d0 = 0.f, d1 = 0.f, d2 = 0.f, d3 = 0.f;
        #pragma unroll 4
        for (int c = 0; c < EDIM; c += 16) {
            float4 e0 = *(const float4*)(er + c);
            float4 e1 = *(const float4*)(er + c + 4);
            float4 e2 = *(const float4*)(er + c + 8);
            float4 e3 = *(const float4*)(er + c + 12);
            d0 += e0.x * zs[c]      + e0.y * zs[c + 1]  + e0.z * zs[c + 2]  + e0.w * zs[c + 3];
            d1 += e1.x * zs[c + 4]  + e1.y * zs[c + 5]  + e1.z * zs[c + 6]  + e1.w * zs[c + 7];
            d2 += e2.x * zs[c + 8]  + e2.y * zs[c + 9]  + e2.z * zs[c + 10] + e2.w * zs[c + 11];
            d3 += e3.x * zs[c + 12] + e3.y * zs[c + 13] + e3.z * zs[c + 14] + e3.w * zs[c + 15];
        }
        float sv = ce2[t] - ((d0 + d1) + (d2 + d3));
        int bi = t;
        #pragma unroll
        for (int msk = 1; msk < 64; msk <<= 1) {
            float ov = __shfl_xor(sv, msk, 64);
            int oi = __shfl_xor(bi, msk, 64);
            if (ov < sv || (ov == sv && oi < bi)) { sv = ov; bi = oi; }
        }
        if ((t & 63) == 0) { rv[t >> 6] = sv; ri[t >> 6] = bi; }
        __syncthreads();
        if (t == 0) {
            float v = rv[0]; int ix = ri[0];
            for (int ww = 1; ww < 4; ww++)
                if (rv[ww] < v || (rv[ww] == v && ri[ww] < ix)) { v = rv[ww]; ix = ri[ww]; }
            int old = idx_i[px];
            if (ix != old) {
                idx_i[px] = ix; idx_f[px] = (float)ix;
                atomicAdd(&hist[ix], 1); atomicSub(&hist[old], 1);
            }
        }
        __syncthreads();
    }
}

// ---------------- round-1 fp32 argmin (fallback only) ----------------------
__global__ __launch_bounds__(256) void k_argmin(const float* __restrict__ z,
                                                const float* __restrict__ emb,
                                                const float* __restrict__ ce2,
                                                int* __restrict__ idx_i,
                                                float* __restrict__ idx_f,
                                                int* __restrict__ hist,
                                                float* __restrict__ loss_acc) {
    __shared__ float zt[32 * 64];
    __shared__ float et[256 * 34];
    __shared__ float znorm_s[64];
    int t = threadIdx.x;
    int n0 = blockIdx.x * 64;
    int b = n0 >> 10;
    int p0 = n0 & 1023;
    const float* zb = z + (size_t)b * EDIM * HW;
    int tc = t & 31, tp = t >> 5;
    float acc[8][8] = {};
    float znorm = 0.f;
    for (int kk = 0; kk < EDIM; kk += 32) {
        #pragma unroll
        for (int i = 0; i < 16; i++) {
            int q = t + 256 * i;
            int code = q >> 4, k2 = q & 15;
            float2 v = *(const float2*)(emb + (size_t)code * EDIM + kk + k2 * 2);
            *(float2*)(et + code * 34 + k2 * 2) = v;
        }
        #pragma unroll
        for (int i = 0; i < 4; i++) {
            int q = t + 256 * i;
            int k = q >> 5, p2 = q & 31;
            float2 v = *(const float2*)(zb + (size_t)(kk + k) * HW + p0 + p2 * 2);
            *(float2*)(zt + k * 64 + p2 * 2) = v;
        }
        __syncthreads();
        if (t < 64) {
            #pragma unroll
            for (int k = 0; k < 32; k++) { float zz = zt[k * 64 + t]; znorm += zz * zz; }
        }
        #pragma unroll 4
        for (int k2 = 0; k2 < 16; k2++) {
            float2 ev[8], za[4], zb2[4];
            #pragma unroll
            for (int u = 0; u < 8; u++)
                ev[u] = *(float2*)(et + (tc + 32 * u) * 34 + k2 * 2);
            #pragma unroll
            for (int j = 0; j < 4; j++)
                za[j] = *(float2*)(zt + (2 * k2) * 64 + tp * 8 + 2 * j);
            #pragma unroll
            for (int j = 0; j < 4; j++)
                zb2[j] = *(float2*)(zt + (2 * k2 + 1) * 64 + tp * 8 + 2 * j);
            #pragma unroll
            for (int p = 0; p < 8; p++) {
                float z0 = (p & 1) ? za[p >> 1].y : za[p >> 1].x;
                float z1 = (p & 1) ? zb2[p >> 1].y : zb2[p >> 1].x;
                #pragma unroll
                for (int u = 0; u < 8; u++)
                    acc[p][u] += z0 * ev[u].x + z1 * ev[u].y;
            }
        }
        __syncthreads();
    }
    if (t < 64) znorm_s[t] = znorm;
    float minv[8];
    int mini[8];
    #pragma unroll
    for (int p = 0; p < 8; p++) { minv[p] = 3.4e38f; mini[p] = 0; }
    #pragma unroll
    for (int u = 0; u < 8; u++) {
        int code = tc + 32 * u;
        float cc2 = ce2[code];
        #pragma unroll
        for (int p = 0; p < 8; p++) {
            float s = cc2 - acc[p][u];
            if (s < minv[p] || (s == minv[p] && code < mini[p])) { minv[p] = s; mini[p] = code; }
        }
    }
    #pragma unroll
    for (int m = 1; m < 32; m <<= 1) {
        #pragma unroll
        for (int p = 0; p < 8; p++) {
            float ov = __shfl_xor(minv[p], m, 64);
            int oi = __shfl_xor(mini[p], m, 64);
            if (ov < minv[p] || (ov == minv[p] && oi < mini[p])) { minv[p] = ov; mini[p] = oi; }
        }
    }
    __syncthreads();
    if (tc == 0) {
        float dsum = 0.f;
        #pragma unroll
        for (int p = 0; p < 8; p++) {
            int lp = tp * 8 + p;
            int n = n0 + lp;
            idx_i[n] = mini[p];
            idx_f[n] = (float)mini[p];
            dsum += znorm_s[lp] + 2.f * minv[p];
            atomicAdd(&hist[mini[p]], 1);
        }
        atomicAdd(loss_acc, dsum);
    }
}

// ---------------- out[b][o][p] = T[o][idx[b][p]] + bias[o] -----------------
// grid (64 o-groups of 16, 16 batches); T slab staged in LDS (16 KB), gathers
// hit LDS instead of 64 random global dwords per thread.
__global__ __launch_bounds__(256) void k_scatter(const float* __restrict__ T,
                                                 const float* __restrict__ bias,
                                                 const int* __restrict__ idx,
                                                 float* __restrict__ out) {
    __shared__ float Ts[16 * 256];
    __shared__ float bs[16];
    int t = threadIdx.x;
    int o0 = blockIdx.x * 16;
    int b = blockIdx.y;
    #pragma unroll
    for (int r = 0; r < 16; r++)
        Ts[r * 256 + t] = T[(size_t)(o0 + r) * NE + t];
    if (t < 16) bs[t] = bias[o0 + t];
    __syncthreads();
    int4 i4 = *(const int4*)(idx + b * HW + t * 4);
    #pragma unroll
    for (int r = 0; r < 16; r++) {
        const float* Tr = Ts + r * 256;
        float bb = bs[r];
        float4 v;
        v.x = Tr[i4.x] + bb;
        v.y = Tr[i4.y] + bb;
        v.z = Tr[i4.z] + bb;
        v.w = Tr[i4.w] + bb;
        *(float4*)(out + ((size_t)(b * EDIM + o0 + r) * HW) + t * 4) = v;
    }
}

// ---------------- finalize -------------------------------------------------
__global__ __launch_bounds__(256) void k_final_new(const int* __restrict__ hist,
                                                   const float* __restrict__ loss_s,
                                                   const float* __restrict__ zsq,
                                                   float* __restrict__ out) {
    __shared__ float red[4];
    int t = threadIdx.x;
    float em = (float)hist[t] * (1.0f / 16384.0f);
    float v = em * logf(em + 1e-10f);
    #pragma unroll
    for (int m = 32; m; m >>= 1) v += __shfl_down(v, m, 64);
    if ((t & 63) == 0) red[t >> 6] = v;
    __syncthreads();
    if (t == 0) {
        float s = red[0] + red[1] + red[2] + red[3];
        out[OUT_ELEMS] = (zsq[0] + 2.f * loss_s[0]) * 1.25f / 16777216.f;
        out[OUT_ELEMS + 1] = expf(-s);
    }
}

__global__ __launch_bounds__(256) void k_final_old(const int* __restrict__ hist,
                                                   const float* __restrict__ loss_acc,
                                                   float* __restrict__ out) {
    __shared__ float red[4];
    int t = threadIdx.x;
    float em = (float)hist[t] * (1.0f / 16384.0f);
    float v = em * logf(em + 1e-10f);
    #pragma unroll
    for (int m = 32; m; m >>= 1) v += __shfl_down(v, m, 64);
    if ((t & 63) == 0) red[t >> 6] = v;
    __syncthreads();
    if (t == 0) {
        float s = red[0] + red[1] + red[2] + red[3];
        out[OUT_ELEMS] = loss_acc[0] * 1.25f / 16777216.f;
        out[OUT_ELEMS + 1] = expf(-s);
    }
}

extern "C" void kernel_launch(void* const* d_in, const int* in_sizes, int n_in,
                              void* d_out, int out_size, void* d_ws, size_t ws_size,
                              hipStream_t stream) {
    (void)in_sizes; (void)n_in; (void)out_size;
    const float* z      = (const float*)d_in[0];
    const float* emb    = (const float*)d_in[1];
    const float* conv_w = (const float*)d_in[2];
    const float* conv_b = (const float*)d_in[3];
    float* out = (float*)d_out;

    if (ws_size >= WS_NEED) {
        // ---- fast path: fused bf16 MFMA distance GEMM, no global scratch ----
        int*   hist     = (int*)((char*)d_ws + WS_HIST);
        float* loss_s   = (float*)((char*)d_ws + WS_LOSS);
        float* zsq      = (float*)((char*)d_ws + WS_ZSQ);
        int*   nflag    = (int*)((char*)d_ws + WS_NFLAG);
        float* T        = (float*)((char*)d_ws + WS_T);
        float* ce2      = (float*)((char*)d_ws + WS_CE2);
        int*   flagged  = (int*)((char*)d_ws + WS_FLAG);
        int*   idx_i    = (int*)((char*)d_ws + WS_IDX);
        unsigned short* eh = (unsigned short*)((char*)d_ws + WS_EH);
        float* idx_f = out + OUT_ELEMS + 2;

        hipMemsetAsync(d_ws, 0, WS_MEMSET, stream);
        k_prep_e<<<256, 256, 0, stream>>>(emb, eh);
        k_norms<<<NE, 64, 0, stream>>>(emb, ce2);
        k_wT<<<dim3(4, 16, 4), 256, 0, stream>>>(conv_w, emb, T);
        k_dist<<<1024, 256, 0, stream>>>(z, eh, ce2, idx_i, idx_f,
                                         hist, loss_s, zsq, nflag, flagged);
        k_cleanup<<<256, 256, 0, stream>>>(z, emb, ce2, nflag, flagged,
                                           idx_i, idx_f, hist);
        k_scatter<<<dim3(64, 16), 256, 0, stream>>>(T, conv_b, idx_i, out);
        k_final_new<<<1, 256, 0, stream>>>(hist, loss_s, zsq, out);
    } else {
        // ---- fallback: round-1 fp32 path ----
        float* ce2      = (float*)((char*)d_ws + WO_CE2);
        int*   hist     = (int*)((char*)d_ws + WO_HIST);
        float* loss_acc = (float*)((char*)d_ws + WO_LOSS);
        int*   idx_i    = (int*)((char*)d_ws + WO_IDX);
        float* T        = (float*)((char*)d_ws + WO_T);
        float* idx_f = out + OUT_ELEMS + 2;

        hipMemsetAsync(d_ws, 0, WO_TOTAL, stream);
        k_norms<<<NE, 64, 0, stream>>>(emb, ce2);
        k_wT<<<dim3(4, 16, 4), 256, 0, stream>>>(conv_w, emb, T);
        k_argmin<<<256, 256, 0, stream>>>(z, emb, ce2, idx_i, idx_f, hist, loss_acc);
        k_scatter<<<dim3(64, 16), 256, 0, stream>>>(T, conv_b, idx_i, out);
        k_final_old<<<1, 256, 0, stream>>>(hist, loss_acc, out);
    }
}

// Round 6
// 304.260 us; speedup vs baseline: 1.3565x; 1.3565x over previous
//
#include <hip/hip_runtime.h>
#include <math.h>

#define NE 256
#define EDIM 1024
#define HW 1024
#define NPIX 16384
#define OUT_ELEMS 16777216

typedef short short8 __attribute__((ext_vector_type(8)));
typedef float f32x4 __attribute__((ext_vector_type(4)));

// ---------------- fast-path workspace layout (bytes) ----------------
// [memset region: hist + ctrl + T]
#define WS_HIST   0          // int[256]
#define WS_LOSS   1024       // float
#define WS_ZSQ    1028       // float
#define WS_NFLAG  1032       // int
#define WS_T      4096       // float[1024*256] = 1 MB
#define WS_MEMSET 1052672
// [no-init region]
#define WS_CE2    1052672    // float[256]
#define WS_FLAG   1053696    // int[16384]
#define WS_IDX    1119232    // int[16384]
#define WS_EH     1184768    // ushort[256*1024] = 512 KB
#define WS_NEED   1709056

#define MAXF 16384           // can hold ALL pixels -> overflow can't drop any
#define DELTA 0.6f           // tie-guard; 1-pass bf16 score-diff sigma ~0.1

// ---------------- fallback (round-1) workspace layout ----------------
#define WO_CE2  0
#define WO_HIST 1024
#define WO_LOSS 2048
#define WO_IDX  4096
#define WO_T    69632
#define WO_TOTAL 1118208

__device__ __forceinline__ unsigned short f2bf(float f) {
    unsigned u = __float_as_uint(f);
    unsigned r = u + 0x7FFFu + ((u >> 16) & 1u);   // RNE
    return (unsigned short)(r >> 16);
}

// async global->LDS, 16 B per lane; lptr must be wave-uniform (HW adds lane*16)
__device__ __forceinline__ void stage16(const void* g, void* l) {
    __builtin_amdgcn_global_load_lds(
        (const __attribute__((address_space(1))) unsigned int*)g,
        (__attribute__((address_space(3))) unsigned int*)l, 16, 0, 0);
}

// ---------------- fused prep: emb -> eh bf16 AND ce2 = 0.5||e||^2 ----------
__global__ __launch_bounds__(64) void k_prep(const float* __restrict__ emb,
                                             unsigned short* __restrict__ eh,
                                             float* __restrict__ ce2) {
    int j = blockIdx.x;
    int l = threadIdx.x;
    const float* row = emb + ((size_t)j << 10);
    float s = 0.f;
    #pragma unroll
    for (int i = 0; i < 4; i++) {
        float4 v = *(const float4*)(row + l * 4 + 256 * i);
        s += v.x * v.x + v.y * v.y + v.z * v.z + v.w * v.w;
        uint2 hp;
        hp.x = (unsigned)f2bf(v.x) | ((unsigned)f2bf(v.y) << 16);
        hp.y = (unsigned)f2bf(v.z) | ((unsigned)f2bf(v.w) << 16);
        *(uint2*)(eh + ((size_t)j << 10) + l * 4 + 256 * i) = hp;
    }
    #pragma unroll
    for (int m = 32; m; m >>= 1) s += __shfl_down(s, m, 64);
    if (l == 0) ce2[j] = 0.5f * s;
}

// ---------------- T[o][j] = sum_c w[o][c]*emb[j][c] (split-K, atomics) ----
__global__ __launch_bounds__(256) void k_wT(const float* __restrict__ w,
                                            const float* __restrict__ emb,
                                            float* __restrict__ T) {
    __shared__ float wt[64 * 17];
    __shared__ float et[64 * 17];
    int t = threadIdx.x;
    int j0 = blockIdx.x * 64;
    int o0 = blockIdx.y * 64;
    int kb = blockIdx.z * 256;
    int to = t & 15, tj = t >> 4;
    float acc[4][4] = {};
    int lr = t >> 2, lk = (t & 3) * 4;
    for (int kk = kb; kk < kb + 256; kk += 16) {
        float4 wv = *(const float4*)(w + (size_t)(o0 + lr) * EDIM + kk + lk);
        float4 ev = *(const float4*)(emb + (size_t)(j0 + lr) * EDIM + kk + lk);
        __syncthreads();
        wt[lr * 17 + lk + 0] = wv.x; wt[lr * 17 + lk + 1] = wv.y;
        wt[lr * 17 + lk + 2] = wv.z; wt[lr * 17 + lk + 3] = wv.w;
        et[lr * 17 + lk + 0] = ev.x; et[lr * 17 + lk + 1] = ev.y;
        et[lr * 17 + lk + 2] = ev.z; et[lr * 17 + lk + 3] = ev.w;
        __syncthreads();
        #pragma unroll
        for (int k = 0; k < 16; k++) {
            float a[4], b[4];
            #pragma unroll
            for (int i = 0; i < 4; i++) a[i] = wt[(to * 4 + i) * 17 + k];
            #pragma unroll
            for (int i = 0; i < 4; i++) b[i] = et[(tj * 4 + i) * 17 + k];
            #pragma unroll
            for (int i = 0; i < 4; i++)
                #pragma unroll
                for (int jx = 0; jx < 4; jx++) acc[i][jx] += a[i] * b[jx];
        }
    }
    #pragma unroll
    for (int i = 0; i < 4; i++)
        #pragma unroll
        for (int jx = 0; jx < 4; jx++)
            atomicAdd(&T[(size_t)(o0 + to * 4 + i) * NE + j0 + tj * 4 + jx],
                      acc[i][jx]);
}

// ---------------- fused distance GEMM + argmin + tie-flagging --------------
// 256 blocks x 256 thr. Block = 64 px; wave w owns px-tile [px0+w*16, +16),
// ALL 256 codes, full K -> no split-K, no inter-wave combine. B (eh bf16)
// double-buffer staged in LDS via global_load_lds(16B); one barrier/chunk,
// stage of chunk k+1 issued before compute of chunk k. A (z) register-
// prefetched one chunk ahead, converted fp32->bf16 inline.
__global__ __launch_bounds__(256) void k_dist(
        const float* __restrict__ z, const unsigned short* __restrict__ eh,
        const float* __restrict__ ce2,
        int* __restrict__ idx_i, float* __restrict__ idx_f,
        int* __restrict__ hist, float* __restrict__ loss_s,
        float* __restrict__ zsq_acc,
        int* __restrict__ nflag, int* __restrict__ flagged) {
    __shared__ unsigned short sB[2][256 * 32];   // 2 x 16 KB: [code][k32]
    int t = threadIdx.x;
    int lane = t & 63, w = t >> 6;
    int m = lane & 15, quad = lane >> 4;
    int px0 = blockIdx.x * 64;          // 64-px blocks never cross a batch image
    int b = px0 >> 10;
    const float* zp = z + (((size_t)b) << 20) + (px0 & 1023) + w * 16 + m;
    int sc = t >> 2, so = (t & 3) * 8;  // staging: code row, k-offset

    f32x4 acc[16];
    #pragma unroll
    for (int nt = 0; nt < 16; nt++) acc[nt] = (f32x4){0.f, 0.f, 0.f, 0.f};

    // stage chunk 0 into buf 0; prefetch A chunk 0
    #pragma unroll
    for (int i = 0; i < 4; i++)
        stage16(eh + (((size_t)(i * 64 + sc)) << 10) + so,
                &sB[0][(i * 256 + w * 64) * 8]);
    float zv[8];
    #pragma unroll
    for (int j = 0; j < 8; j++)
        zv[j] = zp[((size_t)(quad * 8 + j)) << 10];

    float zsq = 0.f;
    for (int ck = 0; ck < 32; ck++) {
        int cur = ck & 1;
        __syncthreads();                 // drains stage(ck)+A(ck); prev buf free
        short8 af;
        #pragma unroll
        for (int j = 0; j < 8; j++) {
            zsq += zv[j] * zv[j];
            ((unsigned short*)&af)[j] = f2bf(zv[j]);
        }
        if (ck < 31) {
            int kk = (ck + 1) * 32;
            #pragma unroll
            for (int i = 0; i < 4; i++)
                stage16(eh + (((size_t)(i * 64 + sc)) << 10) + kk + so,
                        &sB[1 - cur][(i * 256 + w * 64) * 8]);
            #pragma unroll
            for (int j = 0; j < 8; j++)
                zv[j] = zp[((size_t)(kk + quad * 8 + j)) << 10];
        }
        #pragma unroll
        for (int nt = 0; nt < 16; nt++) {
            short8 bf = *(const short8*)&sB[cur][(nt * 16 + m) * 32 + quad * 8];
            acc[nt] = __builtin_amdgcn_mfma_f32_16x16x32_bf16(af, bf, acc[nt], 0, 0, 0);
        }
    }

    // zsq: waves cover disjoint px, full K each
    #pragma unroll
    for (int msk = 32; msk; msk >>= 1) zsq += __shfl_down(zsq, msk, 64);
    if (lane == 0) atomicAdd(zsq_acc, zsq);

    // ----- per-wave epilogue: argmin over 256 codes for 16 px -----
    float c2v[16];
    #pragma unroll
    for (int nt = 0; nt < 16; nt++) c2v[nt] = ce2[nt * 16 + m];

    float lsum = 0.f;
    #pragma unroll
    for (int r = 0; r < 4; r++) {        // D layout: px row = quad*4+r, code col = m
        float v1 = 3.4e38f, v2 = 3.4e38f; int i1 = 0;
        #pragma unroll
        for (int nt = 0; nt < 16; nt++) {
            int code = nt * 16 + m;
            float sv = c2v[nt] - acc[nt][r];   // 0.5||e||^2 - z.e
            if (sv < v1 || (sv == v1 && code < i1)) { v2 = v1; v1 = sv; i1 = code; }
            else v2 = fminf(v2, sv);
        }
        #pragma unroll
        for (int msk = 1; msk < 16; msk <<= 1) {
            float ov1 = __shfl_xor(v1, msk, 64);
            int   oi1 = __shfl_xor(i1, msk, 64);
            float ov2 = __shfl_xor(v2, msk, 64);
            float nv2 = fminf(fminf(v2, ov2), fmaxf(v1, ov1));
            if (ov1 < v1 || (ov1 == v1 && oi1 < i1)) { v1 = ov1; i1 = oi1; }
            v2 = nv2;
        }
        if (m == 0) {
            int px = px0 + w * 16 + quad * 4 + r;
            idx_i[px] = i1;
            idx_f[px] = (float)i1;
            atomicAdd(&hist[i1], 1);
            if (v2 - v1 < DELTA) {
                int pos = atomicAdd(nflag, 1);
                if (pos < MAXF) flagged[pos] = px;
            }
            lsum += v1;
        }
    }
    lsum += __shfl_xor(lsum, 16, 64);
    lsum += __shfl_xor(lsum, 32, 64);
    if (lane == 0) atomicAdd(loss_s, lsum);
}

// ---------------- exact fp32 re-argmin for tie-flagged pixels --------------
__global__ __launch_bounds__(256) void k_cleanup(const float* __restrict__ z,
        const float* __restrict__ emb, const float* __restrict__ ce2,
        const int* __restrict__ nflag, const int* __restrict__ flagged,
        int* __restrict__ idx_i, float* __restrict__ idx_f, int* __restrict__ hist) {
    __shared__ float zs[1024];
    __shared__ float rv[4];
    __shared__ int ri[4];
    int t = threadIdx.x;
    int nf = *nflag; if (nf > MAXF) nf = MAXF;
    const float* er = emb + (size_t)t * EDIM;
    for (int i = blockIdx.x; i < nf; i += gridDim.x) {
        int px = flagged[i];
        int b = px >> 10, p = px & 1023;
        const float* zb = z + (((size_t)b) << 20) + p;
        #pragma unroll
        for (int r = 0; r < 4; r++) {
            int c = t + 256 * r;
            zs[c] = zb[((size_t)c) << 10];
        }
        __syncthreads();
        float d0 = 0.f, d1 = 0.f, d2 = 0.f, d3 = 0.f;
        #pragma unroll 4
        for (int c = 0; c < EDIM; c += 16) {
            float4 e0 = *(const float4*)(er + c);
            float4 e1 = *(const float4*)(er + c + 4);
            float4 e2 = *(const float4*)(er + c + 8);
            float4 e3 = *(const float4*)(er + c + 12);
            d0 += e0.x * zs[c]      + e0.y * zs[c + 1]  + e0.z * zs[c + 2]  + e0.w * zs[c + 3];
            d1 += e1.x * zs[c + 4]  + e1.y * zs[c + 5]  + e1.z * zs[c + 6]  + e1.w * zs[c + 7];
            d2 += e2.x * zs[c + 8]  + e2.y * zs[c + 9]  + e2.z * zs[c + 10] + e2.w * zs[c + 11];
            d3 += e3.x * zs[c + 12] + e3.y * zs[c + 13] + e3.z * zs[c + 14] + e3.w * zs[c + 15];
        }
        float sv = ce2[t] - ((d0 + d1) + (d2 + d3));
        int bi = t;
        #pragma unroll
        for (int msk = 1; msk < 64; msk <<= 1) {
            float ov = __shfl_xor(sv, msk, 64);
            int oi = __shfl_xor(bi, msk, 64);
            if (ov < sv || (ov == sv && oi < bi)) { sv = ov; bi = oi; }
        }
        if ((t & 63) == 0) { rv[t >> 6] = sv; ri[t >> 6] = bi; }
        __syncthreads();
        if (t == 0) {
            float v = rv[0]; int ix = ri[0];
            for (int ww = 1; ww < 4; ww++)
                if (rv[ww] < v || (rv[ww] == v && ri[ww] < ix)) { v = rv[ww]; ix = ri[ww]; }
            int old = idx_i[px];
            if (ix != old) {
                idx_i[px] = ix; idx_f[px] = (float)ix;
                atomicAdd(&hist[ix], 1); atomicSub(&hist[old], 1);
            }
        }
        __syncthreads();
    }
}

// ---------------- round-1 fp32 argmin (fallback only) ----------------------
__global__ __launch_bounds__(64) void k_norms(const float* __restrict__ emb,
                                              float* __restrict__ ce2) {
    int j = blockIdx.x;
    int lane = threadIdx.x;
    const float* row = emb + (size_t)j * EDIM;
    float s = 0.f;
    #pragma unroll
    for (int i = 0; i < EDIM / 64; i++) {
        float v = row[lane + 64 * i];
        s += v * v;
    }
    #pragma unroll
    for (int m = 32; m; m >>= 1) s += __shfl_down(s, m, 64);
    if (lane == 0) ce2[j] = 0.5f * s;
}

__global__ __launch_bounds__(256) void k_argmin(const float* __restrict__ z,
                                                const float* __restrict__ emb,
                                                const float* __restrict__ ce2,
                                                int* __restrict__ idx_i,
                                                float* __restrict__ idx_f,
                                                int* __restrict__ hist,
                                                float* __restrict__ loss_acc) {
    __shared__ float zt[32 * 64];
    __shared__ float et[256 * 34];
    __shared__ float znorm_s[64];
    int t = threadIdx.x;
    int n0 = blockIdx.x * 64;
    int b = n0 >> 10;
    int p0 = n0 & 1023;
    const float* zb = z + (size_t)b * EDIM * HW;
    int tc = t & 31, tp = t >> 5;
    float acc[8][8] = {};
    float znorm = 0.f;
    for (int kk = 0; kk < EDIM; kk += 32) {
        #pragma unroll
        for (int i = 0; i < 16; i++) {
            int q = t + 256 * i;
            int code = q >> 4, k2 = q & 15;
            float2 v = *(const float2*)(emb + (size_t)code * EDIM + kk + k2 * 2);
            *(float2*)(et + code * 34 + k2 * 2) = v;
        }
        #pragma unroll
        for (int i = 0; i < 4; i++) {
            int q = t + 256 * i;
            int k = q >> 5, p2 = q & 31;
            float2 v = *(const float2*)(zb + (size_t)(kk + k) * HW + p0 + p2 * 2);
            *(float2*)(zt + k * 64 + p2 * 2) = v;
        }
        __syncthreads();
        if (t < 64) {
            #pragma unroll
            for (int k = 0; k < 32; k++) { float zz = zt[k * 64 + t]; znorm += zz * zz; }
        }
        #pragma unroll 4
        for (int k2 = 0; k2 < 16; k2++) {
            float2 ev[8], za[4], zb2[4];
            #pragma unroll
            for (int u = 0; u < 8; u++)
                ev[u] = *(float2*)(et + (tc + 32 * u) * 34 + k2 * 2);
            #pragma unroll
            for (int j = 0; j < 4; j++)
                za[j] = *(float2*)(zt + (2 * k2) * 64 + tp * 8 + 2 * j);
            #pragma unroll
            for (int j = 0; j < 4; j++)
                zb2[j] = *(float2*)(zt + (2 * k2 + 1) * 64 + tp * 8 + 2 * j);
            #pragma unroll
            for (int p = 0; p < 8; p++) {
                float z0 = (p & 1) ? za[p >> 1].y : za[p >> 1].x;
                float z1 = (p & 1) ? zb2[p >> 1].y : zb2[p >> 1].x;
                #pragma unroll
                for (int u = 0; u < 8; u++)
                    acc[p][u] += z0 * ev[u].x + z1 * ev[u].y;
            }
        }
        __syncthreads();
    }
    if (t < 64) znorm_s[t] = znorm;
    float minv[8];
    int mini[8];
    #pragma unroll
    for (int p = 0; p < 8; p++) { minv[p] = 3.4e38f; mini[p] = 0; }
    #pragma unroll
    for (int u = 0; u < 8; u++) {
        int code = tc + 32 * u;
        float cc2 = ce2[code];
        #pragma unroll
        for (int p = 0; p < 8; p++) {
            float s = cc2 - acc[p][u];
            if (s < minv[p] || (s == minv[p] && code < mini[p])) { minv[p] = s; mini[p] = code; }
        }
    }
    #pragma unroll
    for (int m = 1; m < 32; m <<= 1) {
        #pragma unroll
        for (int p = 0; p < 8; p++) {
            float ov = __shfl_xor(minv[p], m, 64);
            int oi = __shfl_xor(mini[p], m, 64);
            if (ov < minv[p] || (ov == minv[p] && oi < mini[p])) { minv[p] = ov; mini[p] = oi; }
        }
    }
    __syncthreads();
    if (tc == 0) {
        float dsum = 0.f;
        #pragma unroll
        for (int p = 0; p < 8; p++) {
            int lp = tp * 8 + p;
            int n = n0 + lp;
            idx_i[n] = mini[p];
            idx_f[n] = (float)mini[p];
            dsum += znorm_s[lp] + 2.f * minv[p];
            atomicAdd(&hist[mini[p]], 1);
        }
        atomicAdd(loss_acc, dsum);
    }
}

// ---------------- out[b][o][p] = T[o][idx[b][p]] + bias[o] -----------------
__global__ __launch_bounds__(256) void k_scatter(const float* __restrict__ T,
                                                 const float* __restrict__ bias,
                                                 const int* __restrict__ idx,
                                                 float* __restrict__ out) {
    __shared__ float Ts[16 * 256];
    __shared__ float bs[16];
    int t = threadIdx.x;
    int o0 = blockIdx.x * 16;
    int b = blockIdx.y;
    #pragma unroll
    for (int r = 0; r < 16; r++)
        Ts[r * 256 + t] = T[(size_t)(o0 + r) * NE + t];
    if (t < 16) bs[t] = bias[o0 + t];
    __syncthreads();
    int4 i4 = *(const int4*)(idx + b * HW + t * 4);
    #pragma unroll
    for (int r = 0; r < 16; r++) {
        const float* Tr = Ts + r * 256;
        float bb = bs[r];
        float4 v;
        v.x = Tr[i4.x] + bb;
        v.y = Tr[i4.y] + bb;
        v.z = Tr[i4.z] + bb;
        v.w = Tr[i4.w] + bb;
        *(float4*)(out + ((size_t)(b * EDIM + o0 + r) * HW) + t * 4) = v;
    }
}

// ---------------- finalize -------------------------------------------------
__global__ __launch_bounds__(256) void k_final_new(const int* __restrict__ hist,
                                                   const float* __restrict__ loss_s,
                                                   const float* __restrict__ zsq,
                                                   float* __restrict__ out) {
    __shared__ float red[4];
    int t = threadIdx.x;
    float em = (float)hist[t] * (1.0f / 16384.0f);
    float v = em * logf(em + 1e-10f);
    #pragma unroll
    for (int m = 32; m; m >>= 1) v += __shfl_down(v, m, 64);
    if ((t & 63) == 0) red[t >> 6] = v;
    __syncthreads();
    if (t == 0) {
        float s = red[0] + red[1] + red[2] + red[3];
        out[OUT_ELEMS] = (zsq[0] + 2.f * loss_s[0]) * 1.25f / 16777216.f;
        out[OUT_ELEMS + 1] = expf(-s);
    }
}

__global__ __launch_bounds__(256) void k_final_old(const int* __restrict__ hist,
                                                   const float* __restrict__ loss_acc,
                                                   float* __restrict__ out) {
    __shared__ float red[4];
    int t = threadIdx.x;
    float em = (float)hist[t] * (1.0f / 16384.0f);
    float v = em * logf(em + 1e-10f);
    #pragma unroll
    for (int m = 32; m; m >>= 1) v += __shfl_down(v, m, 64);
    if ((t & 63) == 0) red[t >> 6] = v;
    __syncthreads();
    if (t == 0) {
        float s = red[0] + red[1] + red[2] + red[3];
        out[OUT_ELEMS] = loss_acc[0] * 1.25f / 16777216.f;
        out[OUT_ELEMS + 1] = expf(-s);
    }
}

extern "C" void kernel_launch(void* const* d_in, const int* in_sizes, int n_in,
                              void* d_out, int out_size, void* d_ws, size_t ws_size,
                              hipStream_t stream) {
    (void)in_sizes; (void)n_in; (void)out_size;
    const float* z      = (const float*)d_in[0];
    const float* emb    = (const float*)d_in[1];
    const float* conv_w = (const float*)d_in[2];
    const float* conv_b = (const float*)d_in[3];
    float* out = (float*)d_out;

    if (ws_size >= WS_NEED) {
        // ---- fast path: LDS-staged 64-px MFMA distance GEMM ----
        int*   hist     = (int*)((char*)d_ws + WS_HIST);
        float* loss_s   = (float*)((char*)d_ws + WS_LOSS);
        float* zsq      = (float*)((char*)d_ws + WS_ZSQ);
        int*   nflag    = (int*)((char*)d_ws + WS_NFLAG);
        float* T        = (float*)((char*)d_ws + WS_T);
        float* ce2      = (float*)((char*)d_ws + WS_CE2);
        int*   flagged  = (int*)((char*)d_ws + WS_FLAG);
        int*   idx_i    = (int*)((char*)d_ws + WS_IDX);
        unsigned short* eh = (unsigned short*)((char*)d_ws + WS_EH);
        float* idx_f = out + OUT_ELEMS + 2;

        hipMemsetAsync(d_ws, 0, WS_MEMSET, stream);
        k_prep<<<NE, 64, 0, stream>>>(emb, eh, ce2);
        k_wT<<<dim3(4, 16, 4), 256, 0, stream>>>(conv_w, emb, T);
        k_dist<<<256, 256, 0, stream>>>(z, eh, ce2, idx_i, idx_f,
                                        hist, loss_s, zsq, nflag, flagged);
        k_cleanup<<<256, 256, 0, stream>>>(z, emb, ce2, nflag, flagged,
                                           idx_i, idx_f, hist);
        k_scatter<<<dim3(64, 16), 256, 0, stream>>>(T, conv_b, idx_i, out);
        k_final_new<<<1, 256, 0, stream>>>(hist, loss_s, zsq, out);
    } else {
        // ---- fallback: round-1 fp32 path ----
        float* ce2      = (float*)((char*)d_ws + WO_CE2);
        int*   hist     = (int*)((char*)d_ws + WO_HIST);
        float* loss_acc = (float*)((char*)d_ws + WO_LOSS);
        int*   idx_i    = (int*)((char*)d_ws + WO_IDX);
        float* T        = (float*)((char*)d_ws + WO_T);
        float* idx_f = out + OUT_ELEMS + 2;

        hipMemsetAsync(d_ws, 0, WO_TOTAL, stream);
        k_norms<<<NE, 64, 0, stream>>>(emb, ce2);
        k_wT<<<dim3(4, 16, 4), 256, 0, stream>>>(conv_w, emb, T);
        k_argmin<<<256, 256, 0, stream>>>(z, emb, ce2, idx_i, idx_f, hist, loss_acc);
        k_scatter<<<dim3(64, 16), 256, 0, stream>>>(T, conv_b, idx_i, out);
        k_final_old<<<1, 256, 0, stream>>>(hist, loss_acc, out);
    }
}

// Round 7
// 260.246 us; speedup vs baseline: 1.5859x; 1.1691x over previous
//
#include <hip/hip_runtime.h>
#include <math.h>

#define NE 256
#define EDIM 1024
#define HW 1024
#define NPIX 16384
#define OUT_ELEMS 16777216

typedef short short8 __attribute__((ext_vector_type(8)));
typedef float f32x4 __attribute__((ext_vector_type(4)));

// ---------------- fast-path workspace layout (bytes) ----------------
// [memset region: hist + ctrl + flag-bitmap + T]
#define WS_HIST   0          // int[256]
#define WS_LOSS   1024       // float
#define WS_ZSQ    1028       // float
#define WS_FBITS  2048       // uint[512] bitmap of tie-flagged pixels (2 KB)
#define WS_T      4096       // float[1024*256] = 1 MB
#define WS_MEMSET 1052672
// [no-init region]
#define WS_CE2    1052672    // float[256]
#define WS_IDX    1053696    // int[16384]
#define WS_EH     1119232    // ushort[256*1024] = 512 KB (bf16 high)
#define WS_EL     1643520    // ushort[256*1024] = 512 KB (bf16 residual)
#define WS_NEED   2167808    // <= 2183168 proven available in R2

#define DELTA 0.02f          // tie-guard; bf16x3 score sigma ~2.5e-4 -> ~80 sigma

// ---------------- fallback (round-1) workspace layout ----------------
#define WO_CE2  0
#define WO_HIST 1024
#define WO_LOSS 2048
#define WO_IDX  4096
#define WO_T    69632
#define WO_TOTAL 1118208

__device__ __forceinline__ unsigned short f2bf(float f) {
    unsigned u = __float_as_uint(f);
    unsigned r = u + 0x7FFFu + ((u >> 16) & 1u);   // RNE
    return (unsigned short)(r >> 16);
}
__device__ __forceinline__ float bf2f(unsigned short h) {
    return __uint_as_float(((unsigned)h) << 16);
}

// async global->LDS, 16 B per lane; lptr must be wave-uniform (HW adds lane*16)
__device__ __forceinline__ void stage16(const void* g, void* l) {
    __builtin_amdgcn_global_load_lds(
        (const __attribute__((address_space(1))) unsigned int*)g,
        (__attribute__((address_space(3))) unsigned int*)l, 16, 0, 0);
}

// ------- fused prep: emb -> eh/el bf16 split AND ce2 = 0.5||e||^2 ----------
__global__ __launch_bounds__(64) void k_prep(const float* __restrict__ emb,
                                             unsigned short* __restrict__ eh,
                                             unsigned short* __restrict__ el,
                                             float* __restrict__ ce2) {
    int j = blockIdx.x;
    int l = threadIdx.x;
    const float* row = emb + ((size_t)j << 10);
    float s = 0.f;
    #pragma unroll
    for (int i = 0; i < 4; i++) {
        float4 v = *(const float4*)(row + l * 4 + 256 * i);
        s += v.x * v.x + v.y * v.y + v.z * v.z + v.w * v.w;
        unsigned short h0 = f2bf(v.x), h1 = f2bf(v.y), h2 = f2bf(v.z), h3 = f2bf(v.w);
        uint2 hp, lp;
        hp.x = (unsigned)h0 | ((unsigned)h1 << 16);
        hp.y = (unsigned)h2 | ((unsigned)h3 << 16);
        lp.x = (unsigned)f2bf(v.x - bf2f(h0)) | ((unsigned)f2bf(v.y - bf2f(h1)) << 16);
        lp.y = (unsigned)f2bf(v.z - bf2f(h2)) | ((unsigned)f2bf(v.w - bf2f(h3)) << 16);
        *(uint2*)(eh + ((size_t)j << 10) + l * 4 + 256 * i) = hp;
        *(uint2*)(el + ((size_t)j << 10) + l * 4 + 256 * i) = lp;
    }
    #pragma unroll
    for (int m = 32; m; m >>= 1) s += __shfl_down(s, m, 64);
    if (l == 0) ce2[j] = 0.5f * s;
}

// ---------------- T[o][j] = sum_c w[o][c]*emb[j][c] (split-K, atomics) ----
__global__ __launch_bounds__(256) void k_wT(const float* __restrict__ w,
                                            const float* __restrict__ emb,
                                            float* __restrict__ T) {
    __shared__ float wt[64 * 17];
    __shared__ float et[64 * 17];
    int t = threadIdx.x;
    int j0 = blockIdx.x * 64;
    int o0 = blockIdx.y * 64;
    int kb = blockIdx.z * 256;
    int to = t & 15, tj = t >> 4;
    float acc[4][4] = {};
    int lr = t >> 2, lk = (t & 3) * 4;
    for (int kk = kb; kk < kb + 256; kk += 16) {
        float4 wv = *(const float4*)(w + (size_t)(o0 + lr) * EDIM + kk + lk);
        float4 ev = *(const float4*)(emb + (size_t)(j0 + lr) * EDIM + kk + lk);
        __syncthreads();
        wt[lr * 17 + lk + 0] = wv.x; wt[lr * 17 + lk + 1] = wv.y;
        wt[lr * 17 + lk + 2] = wv.z; wt[lr * 17 + lk + 3] = wv.w;
        et[lr * 17 + lk + 0] = ev.x; et[lr * 17 + lk + 1] = ev.y;
        et[lr * 17 + lk + 2] = ev.z; et[lr * 17 + lk + 3] = ev.w;
        __syncthreads();
        #pragma unroll
        for (int k = 0; k < 16; k++) {
            float a[4], b[4];
            #pragma unroll
            for (int i = 0; i < 4; i++) a[i] = wt[(to * 4 + i) * 17 + k];
            #pragma unroll
            for (int i = 0; i < 4; i++) b[i] = et[(tj * 4 + i) * 17 + k];
            #pragma unroll
            for (int i = 0; i < 4; i++)
                #pragma unroll
                for (int jx = 0; jx < 4; jx++) acc[i][jx] += a[i] * b[jx];
        }
    }
    #pragma unroll
    for (int i = 0; i < 4; i++)
        #pragma unroll
        for (int jx = 0; jx < 4; jx++)
            atomicAdd(&T[(size_t)(o0 + to * 4 + i) * NE + j0 + tj * 4 + jx],
                      acc[i][jx]);
}

// ---------------- fused bf16x3 distance GEMM + argmin + tie-flagging -------
// 256 blocks x 256 thr. Block = 64 px; wave w owns px-tile [px0+w*16, +16),
// ALL 256 codes, full K. S = zh*eh + zh*el + zl*eh (fp32 MFMA accum).
// B (eh,el) double-buffer staged via global_load_lds(16B); one barrier/chunk;
// stage of chunk k+1 issued before compute of chunk k. A (z) register-
// prefetched one chunk ahead, split to zh/zl inline.
__global__ __launch_bounds__(256) void k_dist(
        const float* __restrict__ z, const unsigned short* __restrict__ eh,
        const unsigned short* __restrict__ el,
        const float* __restrict__ ce2,
        int* __restrict__ idx_i, float* __restrict__ idx_f,
        int* __restrict__ hist, float* __restrict__ loss_s,
        float* __restrict__ zsq_acc, unsigned int* __restrict__ fbits) {
    __shared__ unsigned short sB[2][2][256 * 32];   // [buf][h/l][code*32+k]: 64 KB
    int t = threadIdx.x;
    int lane = t & 63, w = t >> 6;
    int m = lane & 15, quad = lane >> 4;
    int px0 = blockIdx.x * 64;          // 64-px blocks never cross a batch image
    int b = px0 >> 10;
    const float* zp = z + (((size_t)b) << 20) + (px0 & 1023) + w * 16 + m;
    int sc = t >> 2, so = (t & 3) * 8;  // staging: code row, k-offset

    f32x4 acc[16];
    #pragma unroll
    for (int nt = 0; nt < 16; nt++) acc[nt] = (f32x4){0.f, 0.f, 0.f, 0.f};

    // stage chunk 0 into buf 0; prefetch A chunk 0
    #pragma unroll
    for (int i = 0; i < 4; i++) {
        stage16(eh + (((size_t)(i * 64 + sc)) << 10) + so, &sB[0][0][(i * 256 + w * 64) * 8]);
        stage16(el + (((size_t)(i * 64 + sc)) << 10) + so, &sB[0][1][(i * 256 + w * 64) * 8]);
    }
    float zv[8];
    #pragma unroll
    for (int j = 0; j < 8; j++)
        zv[j] = zp[((size_t)(quad * 8 + j)) << 10];

    float zsq = 0.f;
    for (int ck = 0; ck < 32; ck++) {
        int cur = ck & 1;
        __syncthreads();                 // drains stage(ck)+A(ck); prev buf free
        short8 ah, al;
        #pragma unroll
        for (int j = 0; j < 8; j++) {
            zsq += zv[j] * zv[j];
            unsigned short h = f2bf(zv[j]);
            ((unsigned short*)&ah)[j] = h;
            ((unsigned short*)&al)[j] = f2bf(zv[j] - bf2f(h));
        }
        if (ck < 31) {
            int kk = (ck + 1) * 32;
            #pragma unroll
            for (int i = 0; i < 4; i++) {
                stage16(eh + (((size_t)(i * 64 + sc)) << 10) + kk + so,
                        &sB[1 - cur][0][(i * 256 + w * 64) * 8]);
                stage16(el + (((size_t)(i * 64 + sc)) << 10) + kk + so,
                        &sB[1 - cur][1][(i * 256 + w * 64) * 8]);
            }
            #pragma unroll
            for (int j = 0; j < 8; j++)
                zv[j] = zp[((size_t)(kk + quad * 8 + j)) << 10];
        }
        #pragma unroll
        for (int nt = 0; nt < 16; nt++) {
            short8 bh = *(const short8*)&sB[cur][0][(nt * 16 + m) * 32 + quad * 8];
            short8 bl = *(const short8*)&sB[cur][1][(nt * 16 + m) * 32 + quad * 8];
            acc[nt] = __builtin_amdgcn_mfma_f32_16x16x32_bf16(ah, bh, acc[nt], 0, 0, 0);
            acc[nt] = __builtin_amdgcn_mfma_f32_16x16x32_bf16(ah, bl, acc[nt], 0, 0, 0);
            acc[nt] = __builtin_amdgcn_mfma_f32_16x16x32_bf16(al, bh, acc[nt], 0, 0, 0);
        }
    }

    // zsq: waves cover disjoint px, full K each
    #pragma unroll
    for (int msk = 32; msk; msk >>= 1) zsq += __shfl_down(zsq, msk, 64);
    if (lane == 0) atomicAdd(zsq_acc, zsq);

    // ----- per-wave epilogue: argmin over 256 codes for 16 px -----
    float c2v[16];
    #pragma unroll
    for (int nt = 0; nt < 16; nt++) c2v[nt] = ce2[nt * 16 + m];

    float lsum = 0.f;
    #pragma unroll
    for (int r = 0; r < 4; r++) {        // D layout: px row = quad*4+r, code col = m
        float v1 = 3.4e38f, v2 = 3.4e38f; int i1 = 0;
        #pragma unroll
        for (int nt = 0; nt < 16; nt++) {
            int code = nt * 16 + m;
            float sv = c2v[nt] - acc[nt][r];   // 0.5||e||^2 - z.e
            if (sv < v1 || (sv == v1 && code < i1)) { v2 = v1; v1 = sv; i1 = code; }
            else v2 = fminf(v2, sv);
        }
        #pragma unroll
        for (int msk = 1; msk < 16; msk <<= 1) {
            float ov1 = __shfl_xor(v1, msk, 64);
            int   oi1 = __shfl_xor(i1, msk, 64);
            float ov2 = __shfl_xor(v2, msk, 64);
            float nv2 = fminf(fminf(v2, ov2), fmaxf(v1, ov1));
            if (ov1 < v1 || (ov1 == v1 && oi1 < i1)) { v1 = ov1; i1 = oi1; }
            v2 = nv2;
        }
        if (m == 0) {
            int px = px0 + w * 16 + quad * 4 + r;
            idx_i[px] = i1;
            idx_f[px] = (float)i1;
            atomicAdd(&hist[i1], 1);
            if (v2 - v1 < DELTA)
                atomicOr(&fbits[px >> 5], 1u << (px & 31));
            lsum += v1;
        }
    }
    lsum += __shfl_xor(lsum, 16, 64);
    lsum += __shfl_xor(lsum, 32, 64);
    if (lane == 0) atomicAdd(loss_s, lsum);
}

// ---------------- exact fp32 re-argmin for tie-flagged pixels --------------
// Grid-stride over all pixels; skip unless flagged in the bitmap (block-
// uniform test). Cooperative z-column gather into LDS, thread t = code t.
__global__ __launch_bounds__(256) void k_cleanup(const float* __restrict__ z,
        const float* __restrict__ emb, const float* __restrict__ ce2,
        const unsigned int* __restrict__ fbits,
        int* __restrict__ idx_i, float* __restrict__ idx_f, int* __restrict__ hist) {
    __shared__ float zs[1024];
    __shared__ float rv[4];
    __shared__ int ri[4];
    int t = threadIdx.x;
    const float* er = emb + (size_t)t * EDIM;
    for (int px = blockIdx.x; px < NPIX; px += gridDim.x) {
        if (!(fbits[px >> 5] & (1u << (px & 31)))) continue;   // uniform per block
        int b = px >> 10, p = px & 1023;
        const float* zb = z + (((size_t)b) << 20) + p;
        #pragma unroll
        for (int r = 0; r < 4; r++) {
            int c = t + 256 * r;
            zs[c] = zb[((size_t)c) << 10];
        }
        __syncthreads();
        float d0 = 0.f, d1 = 0.f, d2 = 0.f, d3 = 0.f;
        #pragma unroll 4
        for (int c = 0; c < EDIM; c += 16) {
            float4 e0 = *(const float4*)(er + c);
            float4 e1 = *(const float4*)(er + c + 4);
            float4 e2 = *(const float4*)(er + c + 8);
            float4 e3 = *(const float4*)(er + c + 12);
            d0 += e0.x * zs[c]      + e0.y * zs[c + 1]  + e0.z * zs[c + 2]  + e0.w * zs[c + 3];
            d1 += e1.x * zs[c + 4]  + e1.y * zs[c + 5]  + e1.z * zs[c + 6]  + e1.w * zs[c + 7];
            d2 += e2.x * zs[c + 8]  + e2.y * zs[c + 9]  + e2.z * zs[c + 10] + e2.w * zs[c + 11];
            d3 += e3.x * zs[c + 12] + e3.y * zs[c + 13] + e3.z * zs[c + 14] + e3.w * zs[c + 15];
        }
        float sv = ce2[t] - ((d0 + d1) + (d2 + d3));
        int bi = t;
        #pragma unroll
        for (int msk = 1; msk < 64; msk <<= 1) {
            float ov = __shfl_xor(sv, msk, 64);
            int oi = __shfl_xor(bi, msk, 64);
            if (ov < sv || (ov == sv && oi < bi)) { sv = ov; bi = oi; }
        }
        if ((t & 63) == 0) { rv[t >> 6] = sv; ri[t >> 6] = bi; }
        __syncthreads();
        if (t == 0) {
            float v = rv[0]; int ix = ri[0];
            for (int ww = 1; ww < 4; ww++)
                if (rv[ww] < v || (rv[ww] == v && ri[ww] < ix)) { v = rv[ww]; ix = ri[ww]; }
            int old = idx_i[px];
            if (ix != old) {
                idx_i[px] = ix; idx_f[px] = (float)ix;
                atomicAdd(&hist[ix], 1); atomicSub(&hist[old], 1);
            }
        }
        __syncthreads();
    }
}

// ---------------- round-1 fp32 argmin (fallback only) ----------------------
__global__ __launch_bounds__(64) void k_norms(const float* __restrict__ emb,
                                              float* __restrict__ ce2) {
    int j = blockIdx.x;
    int lane = threadIdx.x;
    const float* row = emb + (size_t)j * EDIM;
    float s = 0.f;
    #pragma unroll
    for (int i = 0; i < EDIM / 64; i++) {
        float v = row[lane + 64 * i];
        s += v * v;
    }
    #pragma unroll
    for (int m = 32; m; m >>= 1) s += __shfl_down(s, m, 64);
    if (lane == 0) ce2[j] = 0.5f * s;
}

__global__ __launch_bounds__(256) void k_argmin(const float* __restrict__ z,
                                                const float* __restrict__ emb,
                                                const float* __restrict__ ce2,
                                                int* __restrict__ idx_i,
                                                float* __restrict__ idx_f,
                                                int* __restrict__ hist,
                                                float* __restrict__ loss_acc) {
    __shared__ float zt[32 * 64];
    __shared__ float et[256 * 34];
    __shared__ float znorm_s[64];
    int t = threadIdx.x;
    int n0 = blockIdx.x * 64;
    int b = n0 >> 10;
    int p0 = n0 & 1023;
    const float* zb = z + (size_t)b * EDIM * HW;
    int tc = t & 31, tp = t >> 5;
    float acc[8][8] = {};
    float znorm = 0.f;
    for (int kk = 0; kk < EDIM; kk += 32) {
        #pragma unroll
        for (int i = 0; i < 16; i++) {
            int q = t + 256 * i;
            int code = q >> 4, k2 = q & 15;
            float2 v = *(const float2*)(emb + (size_t)code * EDIM + kk + k2 * 2);
            *(float2*)(et + code * 34 + k2 * 2) = v;
        }
        #pragma unroll
        for (int i = 0; i < 4; i++) {
            int q = t + 256 * i;
            int k = q >> 5, p2 = q & 31;
            float2 v = *(const float2*)(zb + (size_t)(kk + k) * HW + p0 + p2 * 2);
            *(float2*)(zt + k * 64 + p2 * 2) = v;
        }
        __syncthreads();
        if (t < 64) {
            #pragma unroll
            for (int k = 0; k < 32; k++) { float zz = zt[k * 64 + t]; znorm += zz * zz; }
        }
        #pragma unroll 4
        for (int k2 = 0; k2 < 16; k2++) {
            float2 ev[8], za[4], zb2[4];
            #pragma unroll
            for (int u = 0; u < 8; u++)
                ev[u] = *(float2*)(et + (tc + 32 * u) * 34 + k2 * 2);
            #pragma unroll
            for (int j = 0; j < 4; j++)
                za[j] = *(float2*)(zt + (2 * k2) * 64 + tp * 8 + 2 * j);
            #pragma unroll
            for (int j = 0; j < 4; j++)
                zb2[j] = *(float2*)(zt + (2 * k2 + 1) * 64 + tp * 8 + 2 * j);
            #pragma unroll
            for (int p = 0; p < 8; p++) {
                float z0 = (p & 1) ? za[p >> 1].y : za[p >> 1].x;
                float z1 = (p & 1) ? zb2[p >> 1].y : zb2[p >> 1].x;
                #pragma unroll
                for (int u = 0; u < 8; u++)
                    acc[p][u] += z0 * ev[u].x + z1 * ev[u].y;
            }
        }
        __syncthreads();
    }
    if (t < 64) znorm_s[t] = znorm;
    float minv[8];
    int mini[8];
    #pragma unroll
    for (int p = 0; p < 8; p++) { minv[p] = 3.4e38f; mini[p] = 0; }
    #pragma unroll
    for (int u = 0; u < 8; u++) {
        int code = tc + 32 * u;
        float cc2 = ce2[code];
        #pragma unroll
        for (int p = 0; p < 8; p++) {
            float s = cc2 - acc[p][u];
            if (s < minv[p] || (s == minv[p] && code < mini[p])) { minv[p] = s; mini[p] = code; }
        }
    }
    #pragma unroll
    for (int m = 1; m < 32; m <<= 1) {
        #pragma unroll
        for (int p = 0; p < 8; p++) {
            float ov = __shfl_xor(minv[p], m, 64);
            int oi = __shfl_xor(mini[p], m, 64);
            if (ov < minv[p] || (ov == minv[p] && oi < mini[p])) { minv[p] = ov; mini[p] = oi; }
        }
    }
    __syncthreads();
    if (tc == 0) {
        float dsum = 0.f;
        #pragma unroll
        for (int p = 0; p < 8; p++) {
            int lp = tp * 8 + p;
            int n = n0 + lp;
            idx_i[n] = mini[p];
            idx_f[n] = (float)mini[p];
            dsum += znorm_s[lp] + 2.f * minv[p];
            atomicAdd(&hist[mini[p]], 1);
        }
        atomicAdd(loss_acc, dsum);
    }
}

// ---------------- out[b][o][p] = T[o][idx[b][p]] + bias[o] -----------------
__global__ __launch_bounds__(256) void k_scatter(const float* __restrict__ T,
                                                 const float* __restrict__ bias,
                                                 const int* __restrict__ idx,
                                                 float* __restrict__ out) {
    __shared__ float Ts[16 * 256];
    __shared__ float bs[16];
    int t = threadIdx.x;
    int o0 = blockIdx.x * 16;
    int b = blockIdx.y;
    #pragma unroll
    for (int r = 0; r < 16; r++)
        Ts[r * 256 + t] = T[(size_t)(o0 + r) * NE + t];
    if (t < 16) bs[t] = bias[o0 + t];
    __syncthreads();
    int4 i4 = *(const int4*)(idx + b * HW + t * 4);
    #pragma unroll
    for (int r = 0; r < 16; r++) {
        const float* Tr = Ts + r * 256;
        float bb = bs[r];
        float4 v;
        v.x = Tr[i4.x] + bb;
        v.y = Tr[i4.y] + bb;
        v.z = Tr[i4.z] + bb;
        v.w = Tr[i4.w] + bb;
        *(float4*)(out + ((size_t)(b * EDIM + o0 + r) * HW) + t * 4) = v;
    }
}

// ---------------- finalize -------------------------------------------------
__global__ __launch_bounds__(256) void k_final_new(const int* __restrict__ hist,
                                                   const float* __restrict__ loss_s,
                                                   const float* __restrict__ zsq,
                                                   float* __restrict__ out) {
    __shared__ float red[4];
    int t = threadIdx.x;
    float em = (float)hist[t] * (1.0f / 16384.0f);
    float v = em * logf(em + 1e-10f);
    #pragma unroll
    for (int m = 32; m; m >>= 1) v += __shfl_down(v, m, 64);
    if ((t & 63) == 0) red[t >> 6] = v;
    __syncthreads();
    if (t == 0) {
        float s = red[0] + red[1] + red[2] + red[3];
        out[OUT_ELEMS] = (zsq[0] + 2.f * loss_s[0]) * 1.25f / 16777216.f;
        out[OUT_ELEMS + 1] = expf(-s);
    }
}

__global__ __launch_bounds__(256) void k_final_old(const int* __restrict__ hist,
                                                   const float* __restrict__ loss_acc,
                                                   float* __restrict__ out) {
    __shared__ float red[4];
    int t = threadIdx.x;
    float em = (float)hist[t] * (1.0f / 16384.0f);
    float v = em * logf(em + 1e-10f);
    #pragma unroll
    for (int m = 32; m; m >>= 1) v += __shfl_down(v, m, 64);
    if ((t & 63) == 0) red[t >> 6] = v;
    __syncthreads();
    if (t == 0) {
        float s = red[0] + red[1] + red[2] + red[3];
        out[OUT_ELEMS] = loss_acc[0] * 1.25f / 16777216.f;
        out[OUT_ELEMS + 1] = expf(-s);
    }
}

extern "C" void kernel_launch(void* const* d_in, const int* in_sizes, int n_in,
                              void* d_out, int out_size, void* d_ws, size_t ws_size,
                              hipStream_t stream) {
    (void)in_sizes; (void)n_in; (void)out_size;
    const float* z      = (const float*)d_in[0];
    const float* emb    = (const float*)d_in[1];
    const float* conv_w = (const float*)d_in[2];
    const float* conv_b = (const float*)d_in[3];
    float* out = (float*)d_out;

    if (ws_size >= WS_NEED) {
        // ---- fast path: LDS-staged bf16x3 MFMA distance GEMM ----
        int*   hist     = (int*)((char*)d_ws + WS_HIST);
        float* loss_s   = (float*)((char*)d_ws + WS_LOSS);
        float* zsq      = (float*)((char*)d_ws + WS_ZSQ);
        unsigned int* fbits = (unsigned int*)((char*)d_ws + WS_FBITS);
        float* T        = (float*)((char*)d_ws + WS_T);
        float* ce2      = (float*)((char*)d_ws + WS_CE2);
        int*   idx_i    = (int*)((char*)d_ws + WS_IDX);
        unsigned short* eh = (unsigned short*)((char*)d_ws + WS_EH);
        unsigned short* el = (unsigned short*)((char*)d_ws + WS_EL);
        float* idx_f = out + OUT_ELEMS + 2;

        hipMemsetAsync(d_ws, 0, WS_MEMSET, stream);
        k_prep<<<NE, 64, 0, stream>>>(emb, eh, el, ce2);
        k_wT<<<dim3(4, 16, 4), 256, 0, stream>>>(conv_w, emb, T);
        k_dist<<<256, 256, 0, stream>>>(z, eh, el, ce2, idx_i, idx_f,
                                        hist, loss_s, zsq, fbits);
        k_cleanup<<<256, 256, 0, stream>>>(z, emb, ce2, fbits, idx_i, idx_f, hist);
        k_scatter<<<dim3(64, 16), 256, 0, stream>>>(T, conv_b, idx_i, out);
        k_final_new<<<1, 256, 0, stream>>>(hist, loss_s, zsq, out);
    } else {
        // ---- fallback: round-1 fp32 path ----
        float* ce2      = (float*)((char*)d_ws + WO_CE2);
        int*   hist     = (int*)((char*)d_ws + WO_HIST);
        float* loss_acc = (float*)((char*)d_ws + WO_LOSS);
        int*   idx_i    = (int*)((char*)d_ws + WO_IDX);
        float* T        = (float*)((char*)d_ws + WO_T);
        float* idx_f = out + OUT_ELEMS + 2;

        hipMemsetAsync(d_ws, 0, WO_TOTAL, stream);
        k_norms<<<NE, 64, 0, stream>>>(emb, ce2);
        k_wT<<<dim3(4, 16, 4), 256, 0, stream>>>(conv_w, emb, T);
        k_argmin<<<256, 256, 0, stream>>>(z, emb, ce2, idx_i, idx_f, hist, loss_acc);
        k_scatter<<<dim3(64, 16), 256, 0, stream>>>(T, conv_b, idx_i, out);
        k_final_old<<<1, 256, 0, stream>>>(hist, loss_acc, out);
    }
}